// Round 10
// baseline (635.456 us; speedup 1.0000x reference)
//
#include <hip/hip_runtime.h>
#include <cstddef>

// ---------------- problem constants ----------------
constexpr int Gn = 4096;
constexpr int Un = 100000;
constexpr int In = 8192;
constexpr int Fd = 128;
constexpr int Mn = 8192;
constexpr int NNZ_RUI = 500000;
constexpr int NNZ_RGU = 8192;
constexpr int NNZ_RGI = 200000;
constexpr int NCH = 8;  // attention i-chunks / partial slabs

// CSR segment table: 0=rui_row 1=rui_col 2=rgu_row 3=rgu_col 4=rgi_row 5=rgi_col
constexpr int SEGL[6] = {Un + 1, In + 1, Gn + 1, Un + 1, Gn + 1, In + 1};
constexpr int segoff(int s) { int o = 0; for (int i = 0; i < s; ++i) o += SEGL[i]; return o; }
constexpr int CNT_TOT = segoff(6);
constexpr int EN[6] = {NNZ_RUI, NNZ_RUI, NNZ_RGU, NNZ_RGU, NNZ_RGI, NNZ_RGI};
constexpr int eoff(int s) { int o = 0; for (int i = 0; i < s; ++i) o += EN[i]; return o; }
constexpr int E_TOT = eoff(6);
constexpr int SCAN_BLK = 2048;
constexpr int MAXNB = (Un + 1 + SCAN_BLK - 1) / SCAN_BLK;  // 49

constexpr int SOFF[6] = {segoff(0), segoff(1), segoff(2), segoff(3), segoff(4), segoff(5)};
constexpr int EOFF[6] = {eoff(0), eoff(1), eoff(2), eoff(3), eoff(4), eoff(5)};

// merged-kernel block tables
constexpr int HBLK0[7] = {0, 1954, 3908, 3940, 3972, 4754, 5536};  // (EN+255)/256 cumsum
constexpr int CVN[6] = {Un * Fd, Gn * Fd, In * Fd, 5 * Fd * Fd, 5 * Fd * Fd, 5 * Fd * Fd};
constexpr int CVB0[7] = {0, 50000, 52048, 56144, 56464, 56784, 57104};
constexpr int SPN[6] = {Un, Un, In, In, Gn, Gn};
constexpr int SPB0[7] = {0, 25000, 50000, 52048, 54096, 55120, 56144};
// key-range slice shifts per segment (8 contiguous slices over the key space)
constexpr int KSH[6] = {14, 10, 9, 14, 9, 10};  // Un->16384/slice, In->1024, Gn->512
// lin5_all block ranges: user | item | group
constexpr int UB_BLK = (Un + 127) / 128;  // 782
constexpr int IB_BLK = In / 128;          // 64
constexpr int GB_BLK = Gn / 128;          // 32

typedef __attribute__((ext_vector_type(8))) short s8b;
typedef __attribute__((ext_vector_type(4))) short s4b;
typedef __attribute__((ext_vector_type(4))) float f4b;

__device__ __forceinline__ float b2f(short s) {
  union { unsigned u; float f; } v;
  v.u = ((unsigned)(unsigned short)s) << 16;
  return v.f;
}
__device__ __forceinline__ short f2b(float x) {
  union { float f; unsigned u; } v;
  v.f = x;
  unsigned r = (v.u + 0x7fffu + ((v.u >> 16) & 1u)) >> 16;  // RNE
  return (short)r;
}

struct Ptr6i { const int* p[6]; };
struct Ptr6f { const float* p[6]; };
struct CvtArgs { const float* in[6]; short* out[6]; };
struct SpmmArgs { const int* ptr[6]; const int2* pk[6]; const short* x[6]; short* out[6]; };

// ---------------- zero helper ----------------
__global__ void zero_i4(int* __restrict__ p, int n4) {
  int i = blockIdx.x * blockDim.x + threadIdx.x;
  if (i < n4) ((int4*)p)[i] = make_int4(0, 0, 0, 0);
}

// ---------------- merged f32 -> bf16 convert (6 regions, 1 launch) ----------------
__global__ __launch_bounds__(256) void cvt6_kernel(CvtArgs a) {
  int b = blockIdx.x, s = 0;
#pragma unroll
  for (int i = 1; i < 6; ++i) if (b >= CVB0[i]) s = i;
  int idx = (b - CVB0[s]) * 256 + threadIdx.x;
  if (idx < CVN[s]) a.out[s][idx] = f2b(a.in[s][idx]);
}

// ---------------- members gather (bf16 copy) ----------------
__global__ void gather_members(const short* __restrict__ ub, const int* __restrict__ idx,
                               short* __restrict__ mem) {
  int m = blockIdx.x;
  int u = idx[m];
  mem[m * Fd + threadIdx.x] = ub[(size_t)u * Fd + threadIdx.x];
}

// ---------------- merged histogram (6 edge lists, 1 launch) ----------------
__global__ __launch_bounds__(256) void hist6_kernel(Ptr6i keys, int* __restrict__ cnt) {
  int b = blockIdx.x, s = 0;
#pragma unroll
  for (int i = 1; i < 6; ++i) if (b >= HBLK0[i]) s = i;
  int e = (b - HBLK0[s]) * 256 + threadIdx.x;
  if (e < EN[s]) atomicAdd(&cnt[SOFF[s] + keys.p[s][e]], 1);
}

__global__ __launch_bounds__(256) void scanA(const int* __restrict__ cnt, int* __restrict__ ptr,
                                             int* __restrict__ bsum) {
  const int lens[6] = {Un + 1, In + 1, Gn + 1, Un + 1, Gn + 1, In + 1};
  int s = blockIdx.y;
  int len = lens[s];
  int off = 0;
#pragma unroll
  for (int i = 0; i < 6; ++i) if (i < s) off += lens[i];
  int b = blockIdx.x;
  int base = b * SCAN_BLK;
  if (base >= len) return;
  int tid = threadIdx.x;
  int i0 = base + tid * 8;
  int v[8], tsum = 0;
#pragma unroll
  for (int j = 0; j < 8; ++j) {
    int i = i0 + j;
    v[j] = (i < len) ? cnt[off + i] : 0;
    tsum += v[j];
  }
  __shared__ int sd[256];
  sd[tid] = tsum;
  __syncthreads();
  for (int o = 1; o < 256; o <<= 1) {
    int t = (tid >= o) ? sd[tid - o] : 0;
    __syncthreads();
    sd[tid] += t;
    __syncthreads();
  }
  int ex = sd[tid] - tsum;
#pragma unroll
  for (int j = 0; j < 8; ++j) {
    int i = i0 + j;
    if (i < len) ptr[off + i] = ex;
    ex += v[j];
  }
  if (tid == 255) bsum[s * 64 + b] = sd[255];
}

__global__ void scanB(int* __restrict__ bsum) {
  int s = blockIdx.x, t = threadIdx.x;  // 64 threads
  int v = bsum[s * 64 + t];
  int x = v;
#pragma unroll
  for (int o = 1; o < 64; o <<= 1) {
    int y = __shfl_up(x, o, 64);
    if (t >= o) x += y;
  }
  bsum[s * 64 + t] = x - v;
}

__global__ __launch_bounds__(256) void scanC(int* __restrict__ ptr, int* __restrict__ cursor,
                                             const int* __restrict__ bsum) {
  const int lens[6] = {Un + 1, In + 1, Gn + 1, Un + 1, Gn + 1, In + 1};
  int s = blockIdx.y;
  int len = lens[s];
  int off = 0;
#pragma unroll
  for (int i = 0; i < 6; ++i) if (i < s) off += lens[i];
  int b = blockIdx.x;
  int base = b * SCAN_BLK;
  if (base >= len) return;
  int add = bsum[s * 64 + b];
  int i0 = base + threadIdx.x * 8;
#pragma unroll
  for (int j = 0; j < 8; ++j) {
    int i = i0 + j;
    if (i < len) {
      int val = ptr[off + i] + add;
      ptr[off + i] = val;
      cursor[off + i] = val;
    }
  }
}

// ---------------- merged scatter, key-range-sliced for write locality ----------------
// R9 counters: 95us, VALUBusy 0.55%, WRITE_SIZE 84MB vs 11.4MB logical (7.4x
// amplification) -> bound by partial-cache-line writebacks: each 64B line of
// packed holds ~8 edges processed on ~8 different XCDs (non-coherent L2s),
// so the line is written back ~8x byte-masked.
// Fix: 8 key-range slices; slice = blockIdx&7 (consecutive blocks round-robin
// XCDs on MI355X), block only scatters keys in its slice's CONTIGUOUS range ->
// each contiguous packed region is written by ONE XCD -> full lines, ~1x
// writeback. Correctness is mapping-independent (predicate partitions edges
// exactly; per-row order was already atomic-nondeterministic). Keys re-read
// 8x (~45MB, L3-resident).
__global__ __launch_bounds__(256) void scatter6_kernel(Ptr6i keys, Ptr6i gidx, Ptr6f vals,
                                                       int* __restrict__ cursor,
                                                       int2* __restrict__ packed) {
  int bx = blockIdx.x;
  int slice = bx & 7;
  int b = bx >> 3;
  int s = 0;
#pragma unroll
  for (int i = 1; i < 6; ++i) if (b >= HBLK0[i]) s = i;
  int e = (b - HBLK0[s]) * 256 + threadIdx.x;
  if (e >= EN[s]) return;
  int k = keys.p[s][e];
  if ((k >> KSH[s]) != slice) return;
  int pos = atomicAdd(&cursor[SOFF[s] + k], 1);
  union { float f; int i; } u;
  u.f = vals.p[s][e];
  packed[EOFF[s] + pos] = make_int2(gidx.p[s][e], u.i);
}

// ---------------- merged CSR SpMM (6 products, 1 launch; unroll-4 batched) ----------------
__global__ __launch_bounds__(256) void spmm6_kernel(SpmmArgs a) {
  int b = blockIdx.x, s = 0;
#pragma unroll
  for (int i = 1; i < 6; ++i) if (b >= SPB0[i]) s = i;
  int r = (b - SPB0[s]) * 4 + (threadIdx.x >> 6);
  if (r >= SPN[s]) return;
  int lane = threadIdx.x & 63;
  const int* ptr = a.ptr[s];
  const int2* packed = a.pk[s];
  const short* x = a.x[s];
  int st = ptr[r], e = ptr[r + 1];
  float a0 = 0.f, a1 = 0.f;
  int j = st;
  for (; j + 4 <= e; j += 4) {
    int2 e0 = packed[j], e1 = packed[j + 1], e2 = packed[j + 2], e3 = packed[j + 3];
    unsigned x0 = *(const unsigned*)(x + (size_t)e0.x * Fd + lane * 2);
    unsigned x1 = *(const unsigned*)(x + (size_t)e1.x * Fd + lane * 2);
    unsigned x2 = *(const unsigned*)(x + (size_t)e2.x * Fd + lane * 2);
    unsigned x3 = *(const unsigned*)(x + (size_t)e3.x * Fd + lane * 2);
    union { int i; float f; } u0, u1, u2, u3;
    u0.i = e0.y; u1.i = e1.y; u2.i = e2.y; u3.i = e3.y;
    a0 += u0.f * b2f((short)(x0 & 0xffffu)); a1 += u0.f * b2f((short)(x0 >> 16));
    a0 += u1.f * b2f((short)(x1 & 0xffffu)); a1 += u1.f * b2f((short)(x1 >> 16));
    a0 += u2.f * b2f((short)(x2 & 0xffffu)); a1 += u2.f * b2f((short)(x2 >> 16));
    a0 += u3.f * b2f((short)(x3 & 0xffffu)); a1 += u3.f * b2f((short)(x3 >> 16));
  }
  for (; j < e; ++j) {
    int2 ed = packed[j];
    union { int i; float f; } u;
    u.i = ed.y;
    unsigned xv = *(const unsigned*)(x + (size_t)ed.x * Fd + lane * 2);
    a0 += u.f * b2f((short)(xv & 0xffffu));
    a1 += u.f * b2f((short)(xv >> 16));
  }
  unsigned o = ((unsigned)(unsigned short)f2b(a0)) | (((unsigned)(unsigned short)f2b(a1)) << 16);
  *(unsigned*)(a.out[s] + (size_t)r * Fd + lane * 2) = o;
}

// ---------------- single CSR SpMM (att_item -> e_att_g; same unroll-4) ----------------
__global__ __launch_bounds__(256) void spmm_csr_kernel(
    const int* __restrict__ ptr, const int2* __restrict__ packed,
    const short* __restrict__ x, short* __restrict__ out, int n) {
  int r = blockIdx.x * 4 + (threadIdx.x >> 6);
  if (r >= n) return;
  int lane = threadIdx.x & 63;
  int st = ptr[r], e = ptr[r + 1];
  float a0 = 0.f, a1 = 0.f;
  int j = st;
  for (; j + 4 <= e; j += 4) {
    int2 e0 = packed[j], e1 = packed[j + 1], e2 = packed[j + 2], e3 = packed[j + 3];
    unsigned x0 = *(const unsigned*)(x + (size_t)e0.x * Fd + lane * 2);
    unsigned x1 = *(const unsigned*)(x + (size_t)e1.x * Fd + lane * 2);
    unsigned x2 = *(const unsigned*)(x + (size_t)e2.x * Fd + lane * 2);
    unsigned x3 = *(const unsigned*)(x + (size_t)e3.x * Fd + lane * 2);
    union { int i; float f; } u0, u1, u2, u3;
    u0.i = e0.y; u1.i = e1.y; u2.i = e2.y; u3.i = e3.y;
    a0 += u0.f * b2f((short)(x0 & 0xffffu)); a1 += u0.f * b2f((short)(x0 >> 16));
    a0 += u1.f * b2f((short)(x1 & 0xffffu)); a1 += u1.f * b2f((short)(x1 >> 16));
    a0 += u2.f * b2f((short)(x2 & 0xffffu)); a1 += u2.f * b2f((short)(x2 >> 16));
    a0 += u3.f * b2f((short)(x3 & 0xffffu)); a1 += u3.f * b2f((short)(x3 >> 16));
  }
  for (; j < e; ++j) {
    int2 ed = packed[j];
    union { int i; float f; } u;
    u.i = ed.y;
    unsigned xv = *(const unsigned*)(x + (size_t)ed.x * Fd + lane * 2);
    a0 += u.f * b2f((short)(xv & 0xffffu));
    a1 += u.f * b2f((short)(xv >> 16));
  }
  unsigned o = ((unsigned)(unsigned short)f2b(a0)) | (((unsigned)(unsigned short)f2b(a1)) << 16);
  *(unsigned*)(out + (size_t)r * Fd + lane * 2) = o;
}

// ---------------- attention pass A: partial colsum, no atomics ----------------
__global__ __launch_bounds__(256) void attn_colsum_kernel(
    const short* __restrict__ item, const short* __restrict__ mem,
    float* __restrict__ part_cs) {
  int m0 = blockIdx.x * 128, ic = blockIdx.y;
  int tid = threadIdx.x;
  int wave = tid >> 6, lane = tid & 63, wc = wave >> 1;
  int lrow = lane & 15, quad = lane >> 4;
  __shared__ float cs[128];
  if (tid < 128) cs[tid] = 0.f;
  __syncthreads();
  f4b fz = {0.f, 0.f, 0.f, 0.f};
  float ps[4] = {0.f, 0.f, 0.f, 0.f};
  int wr = wave & 1;
  for (int it = 0; it < 8; ++it) {
    int i0 = ic * 1024 + it * 128;
    f4b acc[4][4];
#pragma unroll
    for (int rf = 0; rf < 4; ++rf)
#pragma unroll
      for (int cf = 0; cf < 4; ++cf) acc[rf][cf] = fz;
#pragma unroll
    for (int ks = 0; ks < 4; ++ks) {
      s8b a[4], b[4];
#pragma unroll
      for (int rf = 0; rf < 4; ++rf)
        a[rf] = *(const s8b*)(item + (size_t)(i0 + wr * 64 + rf * 16 + lrow) * Fd + ks * 32 + quad * 8);
#pragma unroll
      for (int cf = 0; cf < 4; ++cf)
        b[cf] = *(const s8b*)(mem + (size_t)(m0 + wc * 64 + cf * 16 + lrow) * Fd + ks * 32 + quad * 8);
#pragma unroll
      for (int rf = 0; rf < 4; ++rf)
#pragma unroll
        for (int cf = 0; cf < 4; ++cf)
          acc[rf][cf] = __builtin_amdgcn_mfma_f32_16x16x32_bf16(a[rf], b[cf], acc[rf][cf], 0, 0, 0);
    }
#pragma unroll
    for (int cf = 0; cf < 4; ++cf)
#pragma unroll
      for (int rf = 0; rf < 4; ++rf)
#pragma unroll
        for (int r = 0; r < 4; ++r) ps[cf] += __expf(acc[rf][cf][r]);
  }
#pragma unroll
  for (int cf = 0; cf < 4; ++cf) {
    float v = ps[cf];
    v += __shfl_xor(v, 16, 64);
    v += __shfl_xor(v, 32, 64);
    if (quad == 0) atomicAdd(&cs[wc * 64 + cf * 16 + lrow], v);
  }
  __syncthreads();
  if (tid < 128) part_cs[ic * Mn + m0 + tid] = cs[tid];
}

// ---------------- MT[f][m] = mem[m][f] / colsum[m] (bf16, 128 x 8192) ----------------
__global__ void mt_build(const short* __restrict__ mem, const float* __restrict__ part_cs,
                         short* __restrict__ MT) {
  int m = blockIdx.x * 64 + (threadIdx.x & 63);
  int w = threadIdx.x >> 6;
  float s = 0.f;
#pragma unroll
  for (int c = 0; c < NCH; ++c) s += part_cs[c * Mn + m];
  float inv = 1.0f / s;
#pragma unroll
  for (int it = 0; it < 4; ++it) {
    int oct = it * 4 + w;  // 0..15 (f octet)
    s8b v = *(const s8b*)(mem + (size_t)m * Fd + oct * 8);
#pragma unroll
    for (int j = 0; j < 8; ++j)
      MT[(size_t)(oct * 8 + j) * Mn + m] = f2b(b2f(v[j]) * inv);
  }
}

// ---------------- attention pass B: part[by] = exp(E) @ MT-chunk ----------------
__global__ __launch_bounds__(256, 2) void attn_out_kernel(
    const short* __restrict__ item, const short* __restrict__ mem,
    const short* __restrict__ MT, float* __restrict__ part) {
  __shared__ short P[128 * 72];
  int i0 = blockIdx.x * 128, by = blockIdx.y;
  int tid = threadIdx.x;
  int wave = tid >> 6, lane = tid & 63, wr = wave & 1, wc = wave >> 1;
  int lrow = lane & 15, quad = lane >> 4;
  f4b fz = {0.f, 0.f, 0.f, 0.f};

  s8b a[4][4];
#pragma unroll
  for (int ks = 0; ks < 4; ++ks)
#pragma unroll
    for (int rf = 0; rf < 4; ++rf)
      a[ks][rf] = *(const s8b*)(item + (size_t)(i0 + wr * 64 + rf * 16 + lrow) * Fd + ks * 32 + quad * 8);

  f4b oacc[4][4];
#pragma unroll
  for (int rf = 0; rf < 4; ++rf)
#pragma unroll
    for (int cf = 0; cf < 4; ++cf) oacc[rf][cf] = fz;

  for (int mt = 0; mt < 16; ++mt) {
    int m0 = by * 1024 + mt * 64;
    f4b eacc[4][2];
#pragma unroll
    for (int rf = 0; rf < 4; ++rf)
#pragma unroll
      for (int cf = 0; cf < 2; ++cf) eacc[rf][cf] = fz;
#pragma unroll
    for (int ks = 0; ks < 4; ++ks) {
      s8b b[2];
#pragma unroll
      for (int cf = 0; cf < 2; ++cf)
        b[cf] = *(const s8b*)(mem + (size_t)(m0 + wc * 32 + cf * 16 + lrow) * Fd + ks * 32 + quad * 8);
#pragma unroll
      for (int rf = 0; rf < 4; ++rf)
#pragma unroll
        for (int cf = 0; cf < 2; ++cf)
          eacc[rf][cf] = __builtin_amdgcn_mfma_f32_16x16x32_bf16(a[ks][rf], b[cf], eacc[rf][cf], 0, 0, 0);
    }
    __syncthreads();
#pragma unroll
    for (int cf = 0; cf < 2; ++cf) {
      int mcol = wc * 32 + cf * 16 + lrow;
#pragma unroll
      for (int rf = 0; rf < 4; ++rf)
#pragma unroll
        for (int r = 0; r < 4; ++r)
          P[(wr * 64 + rf * 16 + quad * 4 + r) * 72 + mcol] = f2b(__expf(eacc[rf][cf][r]));
    }
    __syncthreads();
#pragma unroll
    for (int ks = 0; ks < 2; ++ks) {
      s8b pa[4], b[4];
#pragma unroll
      for (int rf = 0; rf < 4; ++rf)
        pa[rf] = *(const s8b*)&P[(wr * 64 + rf * 16 + lrow) * 72 + ks * 32 + quad * 8];
#pragma unroll
      for (int cf = 0; cf < 4; ++cf)
        b[cf] = *(const s8b*)(MT + (size_t)(wc * 64 + cf * 16 + lrow) * Mn + m0 + ks * 32 + quad * 8);
#pragma unroll
      for (int rf = 0; rf < 4; ++rf)
#pragma unroll
        for (int cf = 0; cf < 4; ++cf)
          oacc[rf][cf] = __builtin_amdgcn_mfma_f32_16x16x32_bf16(pa[rf], b[cf], oacc[rf][cf], 0, 0, 0);
    }
  }
  float* slab = part + (size_t)by * In * Fd;
#pragma unroll
  for (int cf = 0; cf < 4; ++cf) {
    int col = wc * 64 + cf * 16 + lrow;
#pragma unroll
    for (int rf = 0; rf < 4; ++rf)
#pragma unroll
      for (int r = 0; r < 4; ++r) {
        int row = wr * 64 + rf * 16 + quad * 4 + r;
        slab[(size_t)(i0 + row) * Fd + col] = oacc[rf][cf][r];
      }
  }
}

// ---------------- att_item(bf16) = (sum of partials) * item(f32) ----------------
__global__ void reduce_mul_kernel(const float* __restrict__ part, const float* __restrict__ item,
                                  short* __restrict__ out) {
  int i = blockIdx.x * 256 + threadIdx.x;  // f4 index
  f4b s = {0.f, 0.f, 0.f, 0.f};
#pragma unroll
  for (int c = 0; c < NCH; ++c) {
    f4b v = ((const f4b*)(part + (size_t)c * In * Fd))[i];
    s[0] += v[0]; s[1] += v[1]; s[2] += v[2]; s[3] += v[3];
  }
  f4b it = ((const f4b*)item)[i];
  s4b o;
  o[0] = f2b(s[0] * it[0]); o[1] = f2b(s[1] * it[1]);
  o[2] = f2b(s[2] * it[2]); o[3] = f2b(s[3] * it[3]);
  ((s4b*)out)[i] = o;
}

// ---------------- fused lin5 (all 3 branches, 1 launch) ----------------
// Internals = exact R0 structure (proven best). Block range selects branch.
// pat 0 (user/item): segs = [x, A, A*x, B*x, B]
// pat 1 (group):     segs = [x, A, B*x, A*x, C]
__global__ __launch_bounds__(256, 2) void lin5_all_kernel(
    const short* __restrict__ ux, const short* __restrict__ uA, const short* __restrict__ uB,
    const short* __restrict__ uW, const float* __restrict__ ubias, float* __restrict__ uout,
    const short* __restrict__ ix, const short* __restrict__ iA, const short* __restrict__ iB,
    const short* __restrict__ iW, const float* __restrict__ ibias, float* __restrict__ iout,
    const short* __restrict__ gx, const short* __restrict__ gA, const short* __restrict__ gB,
    const short* __restrict__ gC, const short* __restrict__ gW, const float* __restrict__ gbias,
    float* __restrict__ gout) {
  int bx = blockIdx.x;
  const short *x, *A, *B, *C, *W;
  const float* bias;
  float* out;
  int N, pat, n0;
  if (bx < UB_BLK) {
    x = ux; A = uA; B = uB; C = nullptr; W = uW; bias = ubias; out = uout;
    N = Un; pat = 0; n0 = bx * 128;
  } else if (bx < UB_BLK + IB_BLK) {
    x = ix; A = iA; B = iB; C = nullptr; W = iW; bias = ibias; out = iout;
    N = In; pat = 0; n0 = (bx - UB_BLK) * 128;
  } else {
    x = gx; A = gA; B = gB; C = gC; W = gW; bias = gbias; out = gout;
    N = Gn; pat = 1; n0 = (bx - UB_BLK - IB_BLK) * 128;
  }

  __shared__ float bsum[128];
  __shared__ float rs[128];
  int tid = threadIdx.x;
  int wave = tid >> 6, lane = tid & 63, wr = wave & 1, wc = wave >> 1;
  int lrow = lane & 15, quad = lane >> 4;
  if (tid < 128) {
    float s = 0.f;
#pragma unroll
    for (int k = 0; k < 5; ++k) s += bias[k * Fd + tid];
    bsum[tid] = s;
    rs[tid] = 0.f;
  }
  __syncthreads();  // rs/bsum visible before epilogue atomics
  f4b acc[4][4];
  f4b fz = {0.f, 0.f, 0.f, 0.f};
#pragma unroll
  for (int rf = 0; rf < 4; ++rf)
#pragma unroll
    for (int cf = 0; cf < 4; ++cf) acc[rf][cf] = fz;

  const bool full = (n0 + 128 <= N);
  // clamp row for frag loads in the partial tile (garbage rows never stored)
  int rbase = n0 + wr * 64 + lrow;

#pragma unroll
  for (int seg = 0; seg < 5; ++seg) {
    const short* S;
    bool mx;
    if (seg == 0) {
      S = x; mx = false;
    } else if (pat == 0) {
      S = (seg <= 2) ? A : B;
      mx = (seg == 2 || seg == 3);
    } else {
      S = (seg == 1 || seg == 3) ? A : ((seg == 2) ? B : C);
      mx = (seg == 2 || seg == 3);
    }
    const short* Wseg = W + seg * Fd * Fd;
#pragma unroll
    for (int ks = 0; ks < 4; ++ks) {
      s8b bfr[4];
#pragma unroll
      for (int cf = 0; cf < 4; ++cf)
        bfr[cf] = *(const s8b*)(Wseg + (size_t)(wc * 64 + cf * 16 + lrow) * Fd + ks * 32 + quad * 8);
#pragma unroll
      for (int rf = 0; rf < 4; ++rf) {
        int row = rbase + rf * 16;
        if (!full && row >= N) row = N - 1;  // keep loads in-bounds
        size_t off = (size_t)row * Fd + ks * 32 + quad * 8;
        s8b afr = *(const s8b*)(S + off);
        if (mx) {
          s8b xf = *(const s8b*)(x + off);
#pragma unroll
          for (int j = 0; j < 8; ++j) afr[j] = f2b(b2f(afr[j]) * b2f(xf[j]));
        }
#pragma unroll
        for (int cf = 0; cf < 4; ++cf)
          acc[rf][cf] = __builtin_amdgcn_mfma_f32_16x16x32_bf16(afr, bfr[cf], acc[rf][cf], 0, 0, 0);
      }
    }
  }
  // epilogue: bias + LeakyReLU in-place, per-row sum of squares
  float rp[4][4];
#pragma unroll
  for (int rf = 0; rf < 4; ++rf)
#pragma unroll
    for (int r = 0; r < 4; ++r) rp[rf][r] = 0.f;
#pragma unroll
  for (int cf = 0; cf < 4; ++cf) {
    int col = wc * 64 + cf * 16 + lrow;
    float bs = bsum[col];
#pragma unroll
    for (int rf = 0; rf < 4; ++rf)
#pragma unroll
      for (int r = 0; r < 4; ++r) {
        float v = acc[rf][cf][r] + bs;
        v = (v >= 0.f) ? v : 0.01f * v;
        acc[rf][cf][r] = v;
        rp[rf][r] += v * v;
      }
  }
#pragma unroll
  for (int m = 1; m < 16; m <<= 1)
#pragma unroll
    for (int rf = 0; rf < 4; ++rf)
#pragma unroll
      for (int r = 0; r < 4; ++r) rp[rf][r] += __shfl_xor(rp[rf][r], m, 64);
  if (lrow == 0) {
#pragma unroll
    for (int rf = 0; rf < 4; ++rf)
#pragma unroll
      for (int r = 0; r < 4; ++r)
        atomicAdd(&rs[wr * 64 + rf * 16 + quad * 4 + r], rp[rf][r]);
  }
  __syncthreads();
  // normalize + store direct from registers (wave covers 256B contiguous per row)
#pragma unroll
  for (int rf = 0; rf < 4; ++rf)
#pragma unroll
    for (int r = 0; r < 4; ++r) {
      int row = wr * 64 + rf * 16 + quad * 4 + r;
      int n = n0 + row;
      if (full || n < N) {
        float sc = 1.0f / fmaxf(sqrtf(rs[row]), 1e-12f);
#pragma unroll
        for (int cf = 0; cf < 4; ++cf) {
          int col = wc * 64 + cf * 16 + lrow;
          out[(size_t)n * Fd + col] = acc[rf][cf][r] * sc;
        }
      }
    }
}

// ---------------- launch ----------------
extern "C" void kernel_launch(void* const* d_in, const int* in_sizes, int n_in,
                              void* d_out, int out_size, void* d_ws, size_t ws_size,
                              hipStream_t stream) {
  const float* group_emb = (const float*)d_in[0];
  const float* user_emb  = (const float*)d_in[1];
  const float* item_emb  = (const float*)d_in[2];
  const int* member_idx  = (const int*)d_in[3];
  const int* rui_rows = (const int*)d_in[4];
  const int* rui_cols = (const int*)d_in[5];
  const float* rui_vals = (const float*)d_in[6];
  const int* rgu_rows = (const int*)d_in[7];
  const int* rgu_cols = (const int*)d_in[8];
  const float* rgu_vals = (const float*)d_in[9];
  const int* rgi_rows = (const int*)d_in[10];
  const int* rgi_cols = (const int*)d_in[11];
  const float* rgi_vals = (const float*)d_in[12];
  const float* Wu = (const float*)d_in[13];
  const float* bu = (const float*)d_in[14];
  const float* Wi = (const float*)d_in[15];
  const float* bi = (const float*)d_in[16];
  const float* Wg = (const float*)d_in[17];
  const float* bg = (const float*)d_in[18];
  (void)in_sizes; (void)n_in; (void)out_size; (void)ws_size;

  float* part_cs = (float*)d_ws;                     // NCH*M f32
  short* sb = (short*)(part_cs + NCH * Mn);
  short* e_rui_u = sb;                 sb += (size_t)Un * Fd;
  short* e_rgu_u = sb;                 sb += (size_t)Un * Fd;
  short* e_rui_i = sb;                 sb += (size_t)In * Fd;
  short* e_rgi_i = sb;                 sb += (size_t)In * Fd;
  short* e_rgi_g = sb;                 sb += (size_t)Gn * Fd;
  short* e_rgu_g = sb;                 sb += (size_t)Gn * Fd;
  short* e_att_g = sb;                 sb += (size_t)Gn * Fd;
  short* att_item = sb;                sb += (size_t)In * Fd;
  short* user_bf = sb;                 sb += (size_t)Un * Fd;
  short* group_bf = sb;                sb += (size_t)Gn * Fd;
  short* item_bf = sb;                 sb += (size_t)In * Fd;
  short* members_bf = sb;              sb += (size_t)Mn * Fd;
  short* MT = sb;                      sb += (size_t)Fd * Mn;
  short* wu_bf = sb;                   sb += 5 * Fd * Fd;
  short* wi_bf = sb;                   sb += 5 * Fd * Fd;
  short* wg_bf = sb;                   sb += 5 * Fd * Fd;
  int* cnt    = (int*)sb;                            // CNT_TOT
  int* bsum   = cnt + CNT_TOT;                       // 6*64
  int* ptr    = bsum + 6 * 64;                       // CNT_TOT
  int* cursor = ptr + CNT_TOT;                       // CNT_TOT
  int2* packed = (int2*)(cursor + CNT_TOT);          // E_TOT

  // attention partial slabs alias d_out (fully overwritten by lin5 at the end)
  float* part_att = (float*)d_out;                   // NCH * I*F f32 (33.6 MB < 57.5 MB)

  // zero cnt (+bsum)
  {
    int nz = CNT_TOT + 6 * 64;
    int n4 = (nz + 3) / 4;  // may spill into ptr (overwritten later)
    zero_i4<<<(n4 + 255) / 256, 256, 0, stream>>>(cnt, n4);
  }

  // merged bf16 conversions (embeddings + weights): 1 launch
  {
    CvtArgs ca;
    ca.in[0] = user_emb;  ca.out[0] = user_bf;
    ca.in[1] = group_emb; ca.out[1] = group_bf;
    ca.in[2] = item_emb;  ca.out[2] = item_bf;
    ca.in[3] = Wu;        ca.out[3] = wu_bf;
    ca.in[4] = Wi;        ca.out[4] = wi_bf;
    ca.in[5] = Wg;        ca.out[5] = wg_bf;
    cvt6_kernel<<<CVB0[6], 256, 0, stream>>>(ca);
  }
  gather_members<<<Mn, Fd, 0, stream>>>(user_bf, member_idx, members_bf);

  Ptr6i keys = {{rui_rows, rui_cols, rgu_rows, rgu_cols, rgi_rows, rgi_cols}};
  Ptr6i gidx = {{rui_cols, rui_rows, rgu_cols, rgu_rows, rgi_cols, rgi_rows}};
  Ptr6f vals = {{rui_vals, rui_vals, rgu_vals, rgu_vals, rgi_vals, rgi_vals}};

  // merged histograms: 1 launch
  hist6_kernel<<<HBLK0[6], 256, 0, stream>>>(keys, cnt);

  // batched exclusive scans -> row_ptr + cursor
  scanA<<<dim3(MAXNB, 6), 256, 0, stream>>>(cnt, ptr, bsum);
  scanB<<<6, 64, 0, stream>>>(bsum);
  scanC<<<dim3(MAXNB, 6), 256, 0, stream>>>(ptr, cursor, bsum);

  // merged scatter, key-range-sliced: 1 launch (8 slices x chunk-blocks)
  scatter6_kernel<<<HBLK0[6] * 8, 256, 0, stream>>>(keys, gidx, vals, cursor, packed);

  // merged CSR SpMMs: 1 launch
  {
    SpmmArgs sa;
    sa.ptr[0] = ptr + SOFF[0]; sa.pk[0] = packed + EOFF[0]; sa.x[0] = item_bf;  sa.out[0] = e_rui_u;
    sa.ptr[1] = ptr + SOFF[3]; sa.pk[1] = packed + EOFF[3]; sa.x[1] = group_bf; sa.out[1] = e_rgu_u;
    sa.ptr[2] = ptr + SOFF[1]; sa.pk[2] = packed + EOFF[1]; sa.x[2] = user_bf;  sa.out[2] = e_rui_i;
    sa.ptr[3] = ptr + SOFF[5]; sa.pk[3] = packed + EOFF[5]; sa.x[3] = group_bf; sa.out[3] = e_rgi_i;
    sa.ptr[4] = ptr + SOFF[4]; sa.pk[4] = packed + EOFF[4]; sa.x[4] = item_bf;  sa.out[4] = e_rgi_g;
    sa.ptr[5] = ptr + SOFF[2]; sa.pk[5] = packed + EOFF[2]; sa.x[5] = user_bf;  sa.out[5] = e_rgu_g;
    spmm6_kernel<<<SPB0[6], 256, 0, stream>>>(sa);
  }

  // attention: partial colsum -> scaled transpose -> PV with global MT
  attn_colsum_kernel<<<dim3(Mn / 128, NCH), 256, 0, stream>>>(item_bf, members_bf, part_cs);
  mt_build<<<Mn / 64, 256, 0, stream>>>(members_bf, part_cs, MT);
  attn_out_kernel<<<dim3(In / 128, NCH), 256, 0, stream>>>(item_bf, members_bf, MT, part_att);
  reduce_mul_kernel<<<(In * Fd / 4) / 256, 256, 0, stream>>>(part_att, item_emb, att_item);
  spmm_csr_kernel<<<(Gn + 3) / 4, 256, 0, stream>>>(ptr + SOFF[4], packed + EOFF[4], att_item, e_att_g, Gn);

  // fused lin5 (group|user|item in one launch); output order: group | user | item
  float* out_g = (float*)d_out;
  float* out_u = out_g + (size_t)Gn * Fd;
  float* out_i = out_u + (size_t)Un * Fd;
  lin5_all_kernel<<<UB_BLK + IB_BLK + GB_BLK, 256, 0, stream>>>(
      user_bf, e_rui_u, e_rgu_u, wu_bf, bu, out_u,
      item_bf, e_rui_i, e_rgi_i, wi_bf, bi, out_i,
      group_bf, e_rgi_g, e_rgu_g, e_att_g, wg_bf, bg, out_g);
}

// Round 11
// 604.520 us; speedup vs baseline: 1.0512x; 1.0512x over previous
//
#include <hip/hip_runtime.h>
#include <cstddef>

// ---------------- problem constants ----------------
constexpr int Gn = 4096;
constexpr int Un = 100000;
constexpr int In = 8192;
constexpr int Fd = 128;
constexpr int Mn = 8192;
constexpr int NNZ_RUI = 500000;
constexpr int NNZ_RGU = 8192;
constexpr int NNZ_RGI = 200000;
constexpr int NCH = 8;  // attention i-chunks / partial slabs

// CSR segment table: 0=rui_row 1=rui_col 2=rgu_row 3=rgu_col 4=rgi_row 5=rgi_col
constexpr int SEGL[6] = {Un + 1, In + 1, Gn + 1, Un + 1, Gn + 1, In + 1};
constexpr int segoff(int s) { int o = 0; for (int i = 0; i < s; ++i) o += SEGL[i]; return o; }
constexpr int CNT_TOT = segoff(6);
constexpr int EN[6] = {NNZ_RUI, NNZ_RUI, NNZ_RGU, NNZ_RGU, NNZ_RGI, NNZ_RGI};
constexpr int eoff(int s) { int o = 0; for (int i = 0; i < s; ++i) o += EN[i]; return o; }
constexpr int E_TOT = eoff(6);
constexpr int SCAN_BLK = 2048;
constexpr int MAXNB = (Un + 1 + SCAN_BLK - 1) / SCAN_BLK;  // 49

constexpr int SOFF[6] = {segoff(0), segoff(1), segoff(2), segoff(3), segoff(4), segoff(5)};
constexpr int EOFF[6] = {eoff(0), eoff(1), eoff(2), eoff(3), eoff(4), eoff(5)};

// merged-kernel block tables
constexpr int HBLK0[7] = {0, 1954, 3908, 3940, 3972, 4754, 5536};  // (EN+255)/256 cumsum
// cvt6: 8 elements/thread (2048/block)
constexpr int CVN[6] = {Un * Fd, Gn * Fd, In * Fd, 5 * Fd * Fd, 5 * Fd * Fd, 5 * Fd * Fd};
constexpr int CVB0[7] = {0, 6250, 6506, 7018, 7058, 7098, 7138};  // ceil(CVN/2048) cumsum
constexpr int SPN[6] = {Un, Un, In, In, Gn, Gn};
constexpr int SPB0[7] = {0, 25000, 50000, 52048, 54096, 55120, 56144};
// lin5_all block ranges: user | item | group
constexpr int UB_BLK = (Un + 127) / 128;  // 782
constexpr int IB_BLK = In / 128;          // 64
constexpr int GB_BLK = Gn / 128;          // 32

typedef __attribute__((ext_vector_type(8))) short s8b;
typedef __attribute__((ext_vector_type(4))) short s4b;
typedef __attribute__((ext_vector_type(4))) float f4b;

__device__ __forceinline__ float b2f(short s) {
  union { unsigned u; float f; } v;
  v.u = ((unsigned)(unsigned short)s) << 16;
  return v.f;
}
__device__ __forceinline__ short f2b(float x) {
  union { float f; unsigned u; } v;
  v.f = x;
  unsigned r = (v.u + 0x7fffu + ((v.u >> 16) & 1u)) >> 16;  // RNE
  return (short)r;
}

struct Ptr6i { const int* p[6]; };
struct Ptr6f { const float* p[6]; };
struct CvtArgs { const float* in[6]; short* out[6]; };
struct SpmmArgs { const int* ptr[6]; const int2* pk[6]; const short* x[6]; short* out[6]; };

// ---------------- zero helper ----------------
__global__ void zero_i4(int* __restrict__ p, int n4) {
  int i = blockIdx.x * blockDim.x + threadIdx.x;
  if (i < n4) ((int4*)p)[i] = make_int4(0, 0, 0, 0);
}

// ---------------- merged f32 -> bf16 convert (6 regions, 1 launch, 8 elems/thread) ----------------
// G13: scalar 2B bf16 stores gave 128B/wave-store (1/8 of coalescing optimum).
// Vectorize: 2x float4 in, one s8b (16B) out per thread. All CVN divisible by 8.
__global__ __launch_bounds__(256) void cvt6_kernel(CvtArgs a) {
  int b = blockIdx.x, s = 0;
#pragma unroll
  for (int i = 1; i < 6; ++i) if (b >= CVB0[i]) s = i;
  int idx = ((b - CVB0[s]) * 256 + threadIdx.x) * 8;
  if (idx < CVN[s]) {
    const float* in = a.in[s] + idx;
    f4b v0 = *(const f4b*)in;
    f4b v1 = *(const f4b*)(in + 4);
    s8b o;
    o[0] = f2b(v0[0]); o[1] = f2b(v0[1]); o[2] = f2b(v0[2]); o[3] = f2b(v0[3]);
    o[4] = f2b(v1[0]); o[5] = f2b(v1[1]); o[6] = f2b(v1[2]); o[7] = f2b(v1[3]);
    *(s8b*)(a.out[s] + idx) = o;
  }
}

// ---------------- members gather (bf16 copy) ----------------
__global__ void gather_members(const short* __restrict__ ub, const int* __restrict__ idx,
                               short* __restrict__ mem) {
  int m = blockIdx.x;
  int u = idx[m];
  mem[m * Fd + threadIdx.x] = ub[(size_t)u * Fd + threadIdx.x];
}

// ---------------- merged histogram (6 edge lists, 1 launch) ----------------
__global__ __launch_bounds__(256) void hist6_kernel(Ptr6i keys, int* __restrict__ cnt) {
  int b = blockIdx.x, s = 0;
#pragma unroll
  for (int i = 1; i < 6; ++i) if (b >= HBLK0[i]) s = i;
  int e = (b - HBLK0[s]) * 256 + threadIdx.x;
  if (e < EN[s]) atomicAdd(&cnt[SOFF[s] + keys.p[s][e]], 1);
}

__global__ __launch_bounds__(256) void scanA(const int* __restrict__ cnt, int* __restrict__ ptr,
                                             int* __restrict__ bsum) {
  const int lens[6] = {Un + 1, In + 1, Gn + 1, Un + 1, Gn + 1, In + 1};
  int s = blockIdx.y;
  int len = lens[s];
  int off = 0;
#pragma unroll
  for (int i = 0; i < 6; ++i) if (i < s) off += lens[i];
  int b = blockIdx.x;
  int base = b * SCAN_BLK;
  if (base >= len) return;
  int tid = threadIdx.x;
  int i0 = base + tid * 8;
  int v[8], tsum = 0;
#pragma unroll
  for (int j = 0; j < 8; ++j) {
    int i = i0 + j;
    v[j] = (i < len) ? cnt[off + i] : 0;
    tsum += v[j];
  }
  __shared__ int sd[256];
  sd[tid] = tsum;
  __syncthreads();
  for (int o = 1; o < 256; o <<= 1) {
    int t = (tid >= o) ? sd[tid - o] : 0;
    __syncthreads();
    sd[tid] += t;
    __syncthreads();
  }
  int ex = sd[tid] - tsum;
#pragma unroll
  for (int j = 0; j < 8; ++j) {
    int i = i0 + j;
    if (i < len) ptr[off + i] = ex;
    ex += v[j];
  }
  if (tid == 255) bsum[s * 64 + b] = sd[255];
}

__global__ void scanB(int* __restrict__ bsum) {
  int s = blockIdx.x, t = threadIdx.x;  // 64 threads
  int v = bsum[s * 64 + t];
  int x = v;
#pragma unroll
  for (int o = 1; o < 64; o <<= 1) {
    int y = __shfl_up(x, o, 64);
    if (t >= o) x += y;
  }
  bsum[s * 64 + t] = x - v;
}

__global__ __launch_bounds__(256) void scanC(int* __restrict__ ptr, int* __restrict__ cursor,
                                             const int* __restrict__ bsum) {
  const int lens[6] = {Un + 1, In + 1, Gn + 1, Un + 1, Gn + 1, In + 1};
  int s = blockIdx.y;
  int len = lens[s];
  int off = 0;
#pragma unroll
  for (int i = 0; i < 6; ++i) if (i < s) off += lens[i];
  int b = blockIdx.x;
  int base = b * SCAN_BLK;
  if (base >= len) return;
  int add = bsum[s * 64 + b];
  int i0 = base + threadIdx.x * 8;
#pragma unroll
  for (int j = 0; j < 8; ++j) {
    int i = i0 + j;
    if (i < len) {
      int val = ptr[off + i] + add;
      ptr[off + i] = val;
      cursor[off + i] = val;
    }
  }
}

// ---------------- merged scatter (6 edge lists, 1 launch) ----------------
// R10 lesson: key-range slicing cut WRITE 84->60MB but added 44MB of key
// re-reads and ran SLOWER (95->103us); residual write traffic is likely the
// cursor atomics themselves (slicing can't help those). Reverted to the plain
// R9 form (measured best: 95us, total 619).
__global__ __launch_bounds__(256) void scatter6_kernel(Ptr6i keys, Ptr6i gidx, Ptr6f vals,
                                                       int* __restrict__ cursor,
                                                       int2* __restrict__ packed) {
  int b = blockIdx.x, s = 0;
#pragma unroll
  for (int i = 1; i < 6; ++i) if (b >= HBLK0[i]) s = i;
  int e = (b - HBLK0[s]) * 256 + threadIdx.x;
  if (e >= EN[s]) return;
  int k = keys.p[s][e];
  int pos = atomicAdd(&cursor[SOFF[s] + k], 1);
  union { float f; int i; } u;
  u.f = vals.p[s][e];
  packed[EOFF[s] + pos] = make_int2(gidx.p[s][e], u.i);
}

// ---------------- merged CSR SpMM (6 products, 1 launch; unroll-4 batched) ----------------
__global__ __launch_bounds__(256) void spmm6_kernel(SpmmArgs a) {
  int b = blockIdx.x, s = 0;
#pragma unroll
  for (int i = 1; i < 6; ++i) if (b >= SPB0[i]) s = i;
  int r = (b - SPB0[s]) * 4 + (threadIdx.x >> 6);
  if (r >= SPN[s]) return;
  int lane = threadIdx.x & 63;
  const int* ptr = a.ptr[s];
  const int2* packed = a.pk[s];
  const short* x = a.x[s];
  int st = ptr[r], e = ptr[r + 1];
  float a0 = 0.f, a1 = 0.f;
  int j = st;
  for (; j + 4 <= e; j += 4) {
    int2 e0 = packed[j], e1 = packed[j + 1], e2 = packed[j + 2], e3 = packed[j + 3];
    unsigned x0 = *(const unsigned*)(x + (size_t)e0.x * Fd + lane * 2);
    unsigned x1 = *(const unsigned*)(x + (size_t)e1.x * Fd + lane * 2);
    unsigned x2 = *(const unsigned*)(x + (size_t)e2.x * Fd + lane * 2);
    unsigned x3 = *(const unsigned*)(x + (size_t)e3.x * Fd + lane * 2);
    union { int i; float f; } u0, u1, u2, u3;
    u0.i = e0.y; u1.i = e1.y; u2.i = e2.y; u3.i = e3.y;
    a0 += u0.f * b2f((short)(x0 & 0xffffu)); a1 += u0.f * b2f((short)(x0 >> 16));
    a0 += u1.f * b2f((short)(x1 & 0xffffu)); a1 += u1.f * b2f((short)(x1 >> 16));
    a0 += u2.f * b2f((short)(x2 & 0xffffu)); a1 += u2.f * b2f((short)(x2 >> 16));
    a0 += u3.f * b2f((short)(x3 & 0xffffu)); a1 += u3.f * b2f((short)(x3 >> 16));
  }
  for (; j < e; ++j) {
    int2 ed = packed[j];
    union { int i; float f; } u;
    u.i = ed.y;
    unsigned xv = *(const unsigned*)(x + (size_t)ed.x * Fd + lane * 2);
    a0 += u.f * b2f((short)(xv & 0xffffu));
    a1 += u.f * b2f((short)(xv >> 16));
  }
  unsigned o = ((unsigned)(unsigned short)f2b(a0)) | (((unsigned)(unsigned short)f2b(a1)) << 16);
  *(unsigned*)(a.out[s] + (size_t)r * Fd + lane * 2) = o;
}

// ---------------- single CSR SpMM (att_item -> e_att_g; same unroll-4) ----------------
__global__ __launch_bounds__(256) void spmm_csr_kernel(
    const int* __restrict__ ptr, const int2* __restrict__ packed,
    const short* __restrict__ x, short* __restrict__ out, int n) {
  int r = blockIdx.x * 4 + (threadIdx.x >> 6);
  if (r >= n) return;
  int lane = threadIdx.x & 63;
  int st = ptr[r], e = ptr[r + 1];
  float a0 = 0.f, a1 = 0.f;
  int j = st;
  for (; j + 4 <= e; j += 4) {
    int2 e0 = packed[j], e1 = packed[j + 1], e2 = packed[j + 2], e3 = packed[j + 3];
    unsigned x0 = *(const unsigned*)(x + (size_t)e0.x * Fd + lane * 2);
    unsigned x1 = *(const unsigned*)(x + (size_t)e1.x * Fd + lane * 2);
    unsigned x2 = *(const unsigned*)(x + (size_t)e2.x * Fd + lane * 2);
    unsigned x3 = *(const unsigned*)(x + (size_t)e3.x * Fd + lane * 2);
    union { int i; float f; } u0, u1, u2, u3;
    u0.i = e0.y; u1.i = e1.y; u2.i = e2.y; u3.i = e3.y;
    a0 += u0.f * b2f((short)(x0 & 0xffffu)); a1 += u0.f * b2f((short)(x0 >> 16));
    a0 += u1.f * b2f((short)(x1 & 0xffffu)); a1 += u1.f * b2f((short)(x1 >> 16));
    a0 += u2.f * b2f((short)(x2 & 0xffffu)); a1 += u2.f * b2f((short)(x2 >> 16));
    a0 += u3.f * b2f((short)(x3 & 0xffffu)); a1 += u3.f * b2f((short)(x3 >> 16));
  }
  for (; j < e; ++j) {
    int2 ed = packed[j];
    union { int i; float f; } u;
    u.i = ed.y;
    unsigned xv = *(const unsigned*)(x + (size_t)ed.x * Fd + lane * 2);
    a0 += u.f * b2f((short)(xv & 0xffffu));
    a1 += u.f * b2f((short)(xv >> 16));
  }
  unsigned o = ((unsigned)(unsigned short)f2b(a0)) | (((unsigned)(unsigned short)f2b(a1)) << 16);
  *(unsigned*)(out + (size_t)r * Fd + lane * 2) = o;
}

// ---------------- attention pass A: partial colsum, no atomics ----------------
__global__ __launch_bounds__(256) void attn_colsum_kernel(
    const short* __restrict__ item, const short* __restrict__ mem,
    float* __restrict__ part_cs) {
  int m0 = blockIdx.x * 128, ic = blockIdx.y;
  int tid = threadIdx.x;
  int wave = tid >> 6, lane = tid & 63, wc = wave >> 1;
  int lrow = lane & 15, quad = lane >> 4;
  __shared__ float cs[128];
  if (tid < 128) cs[tid] = 0.f;
  __syncthreads();
  f4b fz = {0.f, 0.f, 0.f, 0.f};
  float ps[4] = {0.f, 0.f, 0.f, 0.f};
  int wr = wave & 1;
  for (int it = 0; it < 8; ++it) {
    int i0 = ic * 1024 + it * 128;
    f4b acc[4][4];
#pragma unroll
    for (int rf = 0; rf < 4; ++rf)
#pragma unroll
      for (int cf = 0; cf < 4; ++cf) acc[rf][cf] = fz;
#pragma unroll
    for (int ks = 0; ks < 4; ++ks) {
      s8b a[4], b[4];
#pragma unroll
      for (int rf = 0; rf < 4; ++rf)
        a[rf] = *(const s8b*)(item + (size_t)(i0 + wr * 64 + rf * 16 + lrow) * Fd + ks * 32 + quad * 8);
#pragma unroll
      for (int cf = 0; cf < 4; ++cf)
        b[cf] = *(const s8b*)(mem + (size_t)(m0 + wc * 64 + cf * 16 + lrow) * Fd + ks * 32 + quad * 8);
#pragma unroll
      for (int rf = 0; rf < 4; ++rf)
#pragma unroll
        for (int cf = 0; cf < 4; ++cf)
          acc[rf][cf] = __builtin_amdgcn_mfma_f32_16x16x32_bf16(a[rf], b[cf], acc[rf][cf], 0, 0, 0);
    }
#pragma unroll
    for (int cf = 0; cf < 4; ++cf)
#pragma unroll
      for (int rf = 0; rf < 4; ++rf)
#pragma unroll
        for (int r = 0; r < 4; ++r) ps[cf] += __expf(acc[rf][cf][r]);
  }
#pragma unroll
  for (int cf = 0; cf < 4; ++cf) {
    float v = ps[cf];
    v += __shfl_xor(v, 16, 64);
    v += __shfl_xor(v, 32, 64);
    if (quad == 0) atomicAdd(&cs[wc * 64 + cf * 16 + lrow], v);
  }
  __syncthreads();
  if (tid < 128) part_cs[ic * Mn + m0 + tid] = cs[tid];
}

// ---------------- MT[f][m] = mem[m][f] / colsum[m] (bf16, 128 x 8192) ----------------
__global__ void mt_build(const short* __restrict__ mem, const float* __restrict__ part_cs,
                         short* __restrict__ MT) {
  int m = blockIdx.x * 64 + (threadIdx.x & 63);
  int w = threadIdx.x >> 6;
  float s = 0.f;
#pragma unroll
  for (int c = 0; c < NCH; ++c) s += part_cs[c * Mn + m];
  float inv = 1.0f / s;
#pragma unroll
  for (int it = 0; it < 4; ++it) {
    int oct = it * 4 + w;  // 0..15 (f octet)
    s8b v = *(const s8b*)(mem + (size_t)m * Fd + oct * 8);
#pragma unroll
    for (int j = 0; j < 8; ++j)
      MT[(size_t)(oct * 8 + j) * Mn + m] = f2b(b2f(v[j]) * inv);
  }
}

// ---------------- attention pass B: part[by] = exp(E) @ MT-chunk ----------------
__global__ __launch_bounds__(256, 2) void attn_out_kernel(
    const short* __restrict__ item, const short* __restrict__ mem,
    const short* __restrict__ MT, float* __restrict__ part) {
  __shared__ short P[128 * 72];
  int i0 = blockIdx.x * 128, by = blockIdx.y;
  int tid = threadIdx.x;
  int wave = tid >> 6, lane = tid & 63, wr = wave & 1, wc = wave >> 1;
  int lrow = lane & 15, quad = lane >> 4;
  f4b fz = {0.f, 0.f, 0.f, 0.f};

  s8b a[4][4];
#pragma unroll
  for (int ks = 0; ks < 4; ++ks)
#pragma unroll
    for (int rf = 0; rf < 4; ++rf)
      a[ks][rf] = *(const s8b*)(item + (size_t)(i0 + wr * 64 + rf * 16 + lrow) * Fd + ks * 32 + quad * 8);

  f4b oacc[4][4];
#pragma unroll
  for (int rf = 0; rf < 4; ++rf)
#pragma unroll
    for (int cf = 0; cf < 4; ++cf) oacc[rf][cf] = fz;

  for (int mt = 0; mt < 16; ++mt) {
    int m0 = by * 1024 + mt * 64;
    f4b eacc[4][2];
#pragma unroll
    for (int rf = 0; rf < 4; ++rf)
#pragma unroll
      for (int cf = 0; cf < 2; ++cf) eacc[rf][cf] = fz;
#pragma unroll
    for (int ks = 0; ks < 4; ++ks) {
      s8b b[2];
#pragma unroll
      for (int cf = 0; cf < 2; ++cf)
        b[cf] = *(const s8b*)(mem + (size_t)(m0 + wc * 32 + cf * 16 + lrow) * Fd + ks * 32 + quad * 8);
#pragma unroll
      for (int rf = 0; rf < 4; ++rf)
#pragma unroll
        for (int cf = 0; cf < 2; ++cf)
          eacc[rf][cf] = __builtin_amdgcn_mfma_f32_16x16x32_bf16(a[ks][rf], b[cf], eacc[rf][cf], 0, 0, 0);
    }
    __syncthreads();
#pragma unroll
    for (int cf = 0; cf < 2; ++cf) {
      int mcol = wc * 32 + cf * 16 + lrow;
#pragma unroll
      for (int rf = 0; rf < 4; ++rf)
#pragma unroll
        for (int r = 0; r < 4; ++r)
          P[(wr * 64 + rf * 16 + quad * 4 + r) * 72 + mcol] = f2b(__expf(eacc[rf][cf][r]));
    }
    __syncthreads();
#pragma unroll
    for (int ks = 0; ks < 2; ++ks) {
      s8b pa[4], b[4];
#pragma unroll
      for (int rf = 0; rf < 4; ++rf)
        pa[rf] = *(const s8b*)&P[(wr * 64 + rf * 16 + lrow) * 72 + ks * 32 + quad * 8];
#pragma unroll
      for (int cf = 0; cf < 4; ++cf)
        b[cf] = *(const s8b*)(MT + (size_t)(wc * 64 + cf * 16 + lrow) * Mn + m0 + ks * 32 + quad * 8);
#pragma unroll
      for (int rf = 0; rf < 4; ++rf)
#pragma unroll
        for (int cf = 0; cf < 4; ++cf)
          oacc[rf][cf] = __builtin_amdgcn_mfma_f32_16x16x32_bf16(pa[rf], b[cf], oacc[rf][cf], 0, 0, 0);
    }
  }
  float* slab = part + (size_t)by * In * Fd;
#pragma unroll
  for (int cf = 0; cf < 4; ++cf) {
    int col = wc * 64 + cf * 16 + lrow;
#pragma unroll
    for (int rf = 0; rf < 4; ++rf)
#pragma unroll
      for (int r = 0; r < 4; ++r) {
        int row = wr * 64 + rf * 16 + quad * 4 + r;
        slab[(size_t)(i0 + row) * Fd + col] = oacc[rf][cf][r];
      }
  }
}

// ---------------- att_item(bf16) = (sum of partials) * item(f32) ----------------
__global__ void reduce_mul_kernel(const float* __restrict__ part, const float* __restrict__ item,
                                  short* __restrict__ out) {
  int i = blockIdx.x * 256 + threadIdx.x;  // f4 index
  f4b s = {0.f, 0.f, 0.f, 0.f};
#pragma unroll
  for (int c = 0; c < NCH; ++c) {
    f4b v = ((const f4b*)(part + (size_t)c * In * Fd))[i];
    s[0] += v[0]; s[1] += v[1]; s[2] += v[2]; s[3] += v[3];
  }
  f4b it = ((const f4b*)item)[i];
  s4b o;
  o[0] = f2b(s[0] * it[0]); o[1] = f2b(s[1] * it[1]);
  o[2] = f2b(s[2] * it[2]); o[3] = f2b(s[3] * it[3]);
  ((s4b*)out)[i] = o;
}

// ---------------- fused lin5 (all 3 branches, 1 launch) ----------------
// Internals = exact R0 structure (proven best). Block range selects branch.
// pat 0 (user/item): segs = [x, A, A*x, B*x, B]
// pat 1 (group):     segs = [x, A, B*x, A*x, C]
__global__ __launch_bounds__(256, 2) void lin5_all_kernel(
    const short* __restrict__ ux, const short* __restrict__ uA, const short* __restrict__ uB,
    const short* __restrict__ uW, const float* __restrict__ ubias, float* __restrict__ uout,
    const short* __restrict__ ix, const short* __restrict__ iA, const short* __restrict__ iB,
    const short* __restrict__ iW, const float* __restrict__ ibias, float* __restrict__ iout,
    const short* __restrict__ gx, const short* __restrict__ gA, const short* __restrict__ gB,
    const short* __restrict__ gC, const short* __restrict__ gW, const float* __restrict__ gbias,
    float* __restrict__ gout) {
  int bx = blockIdx.x;
  const short *x, *A, *B, *C, *W;
  const float* bias;
  float* out;
  int N, pat, n0;
  if (bx < UB_BLK) {
    x = ux; A = uA; B = uB; C = nullptr; W = uW; bias = ubias; out = uout;
    N = Un; pat = 0; n0 = bx * 128;
  } else if (bx < UB_BLK + IB_BLK) {
    x = ix; A = iA; B = iB; C = nullptr; W = iW; bias = ibias; out = iout;
    N = In; pat = 0; n0 = (bx - UB_BLK) * 128;
  } else {
    x = gx; A = gA; B = gB; C = gC; W = gW; bias = gbias; out = gout;
    N = Gn; pat = 1; n0 = (bx - UB_BLK - IB_BLK) * 128;
  }

  __shared__ float bsum[128];
  __shared__ float rs[128];
  int tid = threadIdx.x;
  int wave = tid >> 6, lane = tid & 63, wr = wave & 1, wc = wave >> 1;
  int lrow = lane & 15, quad = lane >> 4;
  if (tid < 128) {
    float s = 0.f;
#pragma unroll
    for (int k = 0; k < 5; ++k) s += bias[k * Fd + tid];
    bsum[tid] = s;
    rs[tid] = 0.f;
  }
  __syncthreads();  // rs/bsum visible before epilogue atomics
  f4b acc[4][4];
  f4b fz = {0.f, 0.f, 0.f, 0.f};
#pragma unroll
  for (int rf = 0; rf < 4; ++rf)
#pragma unroll
    for (int cf = 0; cf < 4; ++cf) acc[rf][cf] = fz;

  const bool full = (n0 + 128 <= N);
  // clamp row for frag loads in the partial tile (garbage rows never stored)
  int rbase = n0 + wr * 64 + lrow;

#pragma unroll
  for (int seg = 0; seg < 5; ++seg) {
    const short* S;
    bool mx;
    if (seg == 0) {
      S = x; mx = false;
    } else if (pat == 0) {
      S = (seg <= 2) ? A : B;
      mx = (seg == 2 || seg == 3);
    } else {
      S = (seg == 1 || seg == 3) ? A : ((seg == 2) ? B : C);
      mx = (seg == 2 || seg == 3);
    }
    const short* Wseg = W + seg * Fd * Fd;
#pragma unroll
    for (int ks = 0; ks < 4; ++ks) {
      s8b bfr[4];
#pragma unroll
      for (int cf = 0; cf < 4; ++cf)
        bfr[cf] = *(const s8b*)(Wseg + (size_t)(wc * 64 + cf * 16 + lrow) * Fd + ks * 32 + quad * 8);
#pragma unroll
      for (int rf = 0; rf < 4; ++rf) {
        int row = rbase + rf * 16;
        if (!full && row >= N) row = N - 1;  // keep loads in-bounds
        size_t off = (size_t)row * Fd + ks * 32 + quad * 8;
        s8b afr = *(const s8b*)(S + off);
        if (mx) {
          s8b xf = *(const s8b*)(x + off);
#pragma unroll
          for (int j = 0; j < 8; ++j) afr[j] = f2b(b2f(afr[j]) * b2f(xf[j]));
        }
#pragma unroll
        for (int cf = 0; cf < 4; ++cf)
          acc[rf][cf] = __builtin_amdgcn_mfma_f32_16x16x32_bf16(afr, bfr[cf], acc[rf][cf], 0, 0, 0);
      }
    }
  }
  // epilogue: bias + LeakyReLU in-place, per-row sum of squares
  float rp[4][4];
#pragma unroll
  for (int rf = 0; rf < 4; ++rf)
#pragma unroll
    for (int r = 0; r < 4; ++r) rp[rf][r] = 0.f;
#pragma unroll
  for (int cf = 0; cf < 4; ++cf) {
    int col = wc * 64 + cf * 16 + lrow;
    float bs = bsum[col];
#pragma unroll
    for (int rf = 0; rf < 4; ++rf)
#pragma unroll
      for (int r = 0; r < 4; ++r) {
        float v = acc[rf][cf][r] + bs;
        v = (v >= 0.f) ? v : 0.01f * v;
        acc[rf][cf][r] = v;
        rp[rf][r] += v * v;
      }
  }
#pragma unroll
  for (int m = 1; m < 16; m <<= 1)
#pragma unroll
    for (int rf = 0; rf < 4; ++rf)
#pragma unroll
      for (int r = 0; r < 4; ++r) rp[rf][r] += __shfl_xor(rp[rf][r], m, 64);
  if (lrow == 0) {
#pragma unroll
    for (int rf = 0; rf < 4; ++rf)
#pragma unroll
      for (int r = 0; r < 4; ++r)
        atomicAdd(&rs[wr * 64 + rf * 16 + quad * 4 + r], rp[rf][r]);
  }
  __syncthreads();
  // normalize + store direct from registers (wave covers 256B contiguous per row)
#pragma unroll
  for (int rf = 0; rf < 4; ++rf)
#pragma unroll
    for (int r = 0; r < 4; ++r) {
      int row = wr * 64 + rf * 16 + quad * 4 + r;
      int n = n0 + row;
      if (full || n < N) {
        float sc = 1.0f / fmaxf(sqrtf(rs[row]), 1e-12f);
#pragma unroll
        for (int cf = 0; cf < 4; ++cf) {
          int col = wc * 64 + cf * 16 + lrow;
          out[(size_t)n * Fd + col] = acc[rf][cf][r] * sc;
        }
      }
    }
}

// ---------------- launch ----------------
extern "C" void kernel_launch(void* const* d_in, const int* in_sizes, int n_in,
                              void* d_out, int out_size, void* d_ws, size_t ws_size,
                              hipStream_t stream) {
  const float* group_emb = (const float*)d_in[0];
  const float* user_emb  = (const float*)d_in[1];
  const float* item_emb  = (const float*)d_in[2];
  const int* member_idx  = (const int*)d_in[3];
  const int* rui_rows = (const int*)d_in[4];
  const int* rui_cols = (const int*)d_in[5];
  const float* rui_vals = (const float*)d_in[6];
  const int* rgu_rows = (const int*)d_in[7];
  const int* rgu_cols = (const int*)d_in[8];
  const float* rgu_vals = (const float*)d_in[9];
  const int* rgi_rows = (const int*)d_in[10];
  const int* rgi_cols = (const int*)d_in[11];
  const float* rgi_vals = (const float*)d_in[12];
  const float* Wu = (const float*)d_in[13];
  const float* bu = (const float*)d_in[14];
  const float* Wi = (const float*)d_in[15];
  const float* bi = (const float*)d_in[16];
  const float* Wg = (const float*)d_in[17];
  const float* bg = (const float*)d_in[18];
  (void)in_sizes; (void)n_in; (void)out_size; (void)ws_size;

  float* part_cs = (float*)d_ws;                     // NCH*M f32
  short* sb = (short*)(part_cs + NCH * Mn);
  short* e_rui_u = sb;                 sb += (size_t)Un * Fd;
  short* e_rgu_u = sb;                 sb += (size_t)Un * Fd;
  short* e_rui_i = sb;                 sb += (size_t)In * Fd;
  short* e_rgi_i = sb;                 sb += (size_t)In * Fd;
  short* e_rgi_g = sb;                 sb += (size_t)Gn * Fd;
  short* e_rgu_g = sb;                 sb += (size_t)Gn * Fd;
  short* e_att_g = sb;                 sb += (size_t)Gn * Fd;
  short* att_item = sb;                sb += (size_t)In * Fd;
  short* user_bf = sb;                 sb += (size_t)Un * Fd;
  short* group_bf = sb;                sb += (size_t)Gn * Fd;
  short* item_bf = sb;                 sb += (size_t)In * Fd;
  short* members_bf = sb;              sb += (size_t)Mn * Fd;
  short* MT = sb;                      sb += (size_t)Fd * Mn;
  short* wu_bf = sb;                   sb += 5 * Fd * Fd;
  short* wi_bf = sb;                   sb += 5 * Fd * Fd;
  short* wg_bf = sb;                   sb += 5 * Fd * Fd;
  int* cnt    = (int*)sb;                            // CNT_TOT
  int* bsum   = cnt + CNT_TOT;                       // 6*64
  int* ptr    = bsum + 6 * 64;                       // CNT_TOT
  int* cursor = ptr + CNT_TOT;                       // CNT_TOT
  int2* packed = (int2*)(cursor + CNT_TOT);          // E_TOT

  // attention partial slabs alias d_out (fully overwritten by lin5 at the end)
  float* part_att = (float*)d_out;                   // NCH * I*F f32 (33.6 MB < 57.5 MB)

  // zero cnt (+bsum)
  {
    int nz = CNT_TOT + 6 * 64;
    int n4 = (nz + 3) / 4;  // may spill into ptr (overwritten later)
    zero_i4<<<(n4 + 255) / 256, 256, 0, stream>>>(cnt, n4);
  }

  // merged bf16 conversions (embeddings + weights): 1 launch, 8 elems/thread
  {
    CvtArgs ca;
    ca.in[0] = user_emb;  ca.out[0] = user_bf;
    ca.in[1] = group_emb; ca.out[1] = group_bf;
    ca.in[2] = item_emb;  ca.out[2] = item_bf;
    ca.in[3] = Wu;        ca.out[3] = wu_bf;
    ca.in[4] = Wi;        ca.out[4] = wi_bf;
    ca.in[5] = Wg;        ca.out[5] = wg_bf;
    cvt6_kernel<<<CVB0[6], 256, 0, stream>>>(ca);
  }
  gather_members<<<Mn, Fd, 0, stream>>>(user_bf, member_idx, members_bf);

  Ptr6i keys = {{rui_rows, rui_cols, rgu_rows, rgu_cols, rgi_rows, rgi_cols}};
  Ptr6i gidx = {{rui_cols, rui_rows, rgu_cols, rgu_rows, rgi_cols, rgi_rows}};
  Ptr6f vals = {{rui_vals, rui_vals, rgu_vals, rgu_vals, rgi_vals, rgi_vals}};

  // merged histograms: 1 launch
  hist6_kernel<<<HBLK0[6], 256, 0, stream>>>(keys, cnt);

  // batched exclusive scans -> row_ptr + cursor
  scanA<<<dim3(MAXNB, 6), 256, 0, stream>>>(cnt, ptr, bsum);
  scanB<<<6, 64, 0, stream>>>(bsum);
  scanC<<<dim3(MAXNB, 6), 256, 0, stream>>>(ptr, cursor, bsum);

  // merged scatter: 1 launch (R9 form)
  scatter6_kernel<<<HBLK0[6], 256, 0, stream>>>(keys, gidx, vals, cursor, packed);

  // merged CSR SpMMs: 1 launch
  {
    SpmmArgs sa;
    sa.ptr[0] = ptr + SOFF[0]; sa.pk[0] = packed + EOFF[0]; sa.x[0] = item_bf;  sa.out[0] = e_rui_u;
    sa.ptr[1] = ptr + SOFF[3]; sa.pk[1] = packed + EOFF[3]; sa.x[1] = group_bf; sa.out[1] = e_rgu_u;
    sa.ptr[2] = ptr + SOFF[1]; sa.pk[2] = packed + EOFF[1]; sa.x[2] = user_bf;  sa.out[2] = e_rui_i;
    sa.ptr[3] = ptr + SOFF[5]; sa.pk[3] = packed + EOFF[5]; sa.x[3] = group_bf; sa.out[3] = e_rgi_i;
    sa.ptr[4] = ptr + SOFF[4]; sa.pk[4] = packed + EOFF[4]; sa.x[4] = item_bf;  sa.out[4] = e_rgi_g;
    sa.ptr[5] = ptr + SOFF[2]; sa.pk[5] = packed + EOFF[2]; sa.x[5] = user_bf;  sa.out[5] = e_rgu_g;
    spmm6_kernel<<<SPB0[6], 256, 0, stream>>>(sa);
  }

  // attention: partial colsum -> scaled transpose -> PV with global MT
  attn_colsum_kernel<<<dim3(Mn / 128, NCH), 256, 0, stream>>>(item_bf, members_bf, part_cs);
  mt_build<<<Mn / 64, 256, 0, stream>>>(members_bf, part_cs, MT);
  attn_out_kernel<<<dim3(In / 128, NCH), 256, 0, stream>>>(item_bf, members_bf, MT, part_att);
  reduce_mul_kernel<<<(In * Fd / 4) / 256, 256, 0, stream>>>(part_att, item_emb, att_item);
  spmm_csr_kernel<<<(Gn + 3) / 4, 256, 0, stream>>>(ptr + SOFF[4], packed + EOFF[4], att_item, e_att_g, Gn);

  // fused lin5 (group|user|item in one launch); output order: group | user | item
  float* out_g = (float*)d_out;
  float* out_u = out_g + (size_t)Gn * Fd;
  float* out_i = out_u + (size_t)Un * Fd;
  lin5_all_kernel<<<UB_BLK + IB_BLK + GB_BLK, 256, 0, stream>>>(
      user_bf, e_rui_u, e_rgu_u, wu_bf, bu, out_u,
      item_bf, e_rui_i, e_rgi_i, wi_bf, bi, out_i,
      group_bf, e_rgi_g, e_rgu_g, e_att_g, wg_bf, bg, out_g);
}